// Round 1
// baseline (10495.811 us; speedup 1.0000x reference)
//
#include <hip/hip_runtime.h>
#include <math.h>

#define KTOK 30      // tokens per node
#define HIDC 100     // hidden channels
#define EDIM 200     // TCH + IN_CH
#define BLK  256

// ---------------------------------------------------------------- utilities

__device__ __forceinline__ float gelu_exact(float x) {
    return 0.5f * x * (1.0f + erff(x * 0.70710678118654752f));
}

// ---------------------------------------------------------------- kernel 1: count edges per node
__global__ void count_kernel(const int* __restrict__ nb, int* __restrict__ cnt, int E) {
    int e = blockIdx.x * blockDim.x + threadIdx.x;
    if (e < E) atomicAdd(&cnt[nb[e]], 1);
}

// ---------------------------------------------------------------- kernel 2: exclusive scan (single block)
#define SCAN_T 1024
__global__ void scan_kernel(const int* __restrict__ cnt, int* __restrict__ offsets, int n) {
    __shared__ int sd[SCAN_T];
    __shared__ int srun;
    if (threadIdx.x == 0) srun = 0;
    __syncthreads();
    for (int base = 0; base < n; base += SCAN_T) {
        int i = base + threadIdx.x;
        int v = (i < n) ? cnt[i] : 0;
        sd[threadIdx.x] = v;
        __syncthreads();
        for (int off = 1; off < SCAN_T; off <<= 1) {
            int tv = (threadIdx.x >= off) ? sd[threadIdx.x - off] : 0;
            __syncthreads();
            sd[threadIdx.x] += tv;
            __syncthreads();
        }
        if (i < n) offsets[i] = srun + sd[threadIdx.x] - v;
        int bsum = sd[SCAN_T - 1];
        __syncthreads();
        if (threadIdx.x == 0) srun += bsum;
        __syncthreads();
    }
}

// ---------------------------------------------------------------- kernel 3: bucket fill (unordered within node)
__global__ void fill_kernel(const int* __restrict__ nb, int* __restrict__ cursor,
                            const int* __restrict__ offsets, int* __restrict__ order, int E) {
    int e = blockIdx.x * blockDim.x + threadIdx.x;
    if (e >= E) return;
    int n = nb[e];
    int p = atomicAdd(&cursor[n], 1);
    order[offsets[n] + p] = e;
}

// ---------------------------------------------------------------- kernel 4: per-node select K smallest edge ids (== stable-sort first K)
__global__ void select_kernel(const int* __restrict__ cnt, const int* __restrict__ offsets,
                              const int* __restrict__ order, int* __restrict__ sel, int N) {
    int node = blockIdx.x * blockDim.x + threadIdx.x;
    if (node >= N) return;
    int c = cnt[node];
    int off = offsets[node];
    int top[KTOK];
    int m = 0;
    for (int i = 0; i < c; i++) {
        int e = order[off + i];
        if (m < KTOK) {
            int j = m++;
            while (j > 0 && top[j - 1] > e) { top[j] = top[j - 1]; j--; }
            top[j] = e;
        } else if (e < top[KTOK - 1]) {
            int j = KTOK - 1;
            while (j > 0 && top[j - 1] > e) { top[j] = top[j - 1]; j--; }
            top[j] = e;
        }
    }
    for (int p = 0; p < KTOK; p++) sel[node * KTOK + p] = (p < m) ? top[p] : -1;
}

// ---------------------------------------------------------------- LN helper: one wave per row, rows strided by 4 waves
__device__ __forceinline__ void ln_rows30(const float* __restrict__ src, float* __restrict__ dst,
                                          const float* __restrict__ g, const float* __restrict__ b,
                                          int wave, int lane) {
    for (int k = wave; k < KTOK; k += 4) {
        const float* row = src + k * HIDC;
        float x0 = row[lane];
        float x1 = (lane < 36) ? row[64 + lane] : 0.0f;
        float s = x0 + x1;
        #pragma unroll
        for (int off = 32; off > 0; off >>= 1) s += __shfl_xor(s, off);
        float m = s * 0.01f;
        float d0 = x0 - m;
        float d1 = x1 - m;
        float sq = d0 * d0 + ((lane < 36) ? d1 * d1 : 0.0f);
        #pragma unroll
        for (int off = 32; off > 0; off >>= 1) sq += __shfl_xor(sq, off);
        float rs = rsqrtf(sq * 0.01f + 1e-5f);
        float* drow = dst + k * HIDC;
        drow[lane] = d0 * rs * g[lane] + b[lane];
        if (lane < 36) drow[64 + lane] = d1 * rs * g[64 + lane] + b[64 + lane];
    }
}

// ---------------------------------------------------------------- kernel 5: fused per-node forward
__global__ __launch_bounds__(BLK) void fused_node_kernel(
    const float* __restrict__ edge_attr, const float* __restrict__ edge_time,
    const int* __restrict__ sel,
    const float* __restrict__ head_w, const float* __restrict__ head_b,
    const float* __restrict__ ln_t_g, const float* __restrict__ ln_t_b,
    const float* __restrict__ tok1_w, const float* __restrict__ tok1_b,
    const float* __restrict__ tok2_w, const float* __restrict__ tok2_b,
    const float* __restrict__ ln_c_g, const float* __restrict__ ln_c_b,
    const float* __restrict__ ch1_w, const float* __restrict__ ch1_b,
    const float* __restrict__ ch2_w, const float* __restrict__ ch2_b,
    const float* __restrict__ ln_h_g, const float* __restrict__ ln_h_b,
    const float* __restrict__ out_w, const float* __restrict__ out_b,
    float* __restrict__ out) {
    __shared__ float sU[6000];   // union: IN[30][200] -> y15[100][15] -> H4[15][400]
    __shared__ float sX[3000];   // x -> lnc
    __shared__ float sT[3000];   // lnx -> h_token -> h_channel
    __shared__ float sTW[100];
    __shared__ int   sSel[KTOK];
    __shared__ float sAcc[400];
    __shared__ float sTsum[100];

    const int t = threadIdx.x;
    const int node = blockIdx.x;
    const int wave = t >> 6, lane = t & 63;

    if (t < 100) sTW[t] = exp2f(-3.32192809488736235f * (10.0f * (float)t / 99.0f));
    if (t < KTOK) sSel[t] = sel[node * KTOK + t];
    __syncthreads();

    // ---- Phase A: IN = [cos(t*tw) | edge_attr] then x = IN @ head_w.T + head_b
    for (int idx = t; idx < KTOK * EDIM; idx += BLK) {
        int k = idx / EDIM, c = idx - k * EDIM;
        int e = sSel[k];
        float v = 0.0f;
        if (e >= 0) {
            v = (c < 100) ? cosf(edge_time[e] * sTW[c])
                          : edge_attr[(long long)e * 100 + (c - 100)];
        }
        sU[idx] = v;
    }
    __syncthreads();
    if (t < 200) {
        const int g = t / 100, o = t - g * 100;
        float acc[15];
        #pragma unroll
        for (int kk = 0; kk < 15; kk++) acc[kk] = 0.0f;
        const float* wrow = head_w + o * EDIM;
        for (int c = 0; c < EDIM; c += 4) {
            const float4 w4 = *(const float4*)(wrow + c);
            #pragma unroll
            for (int kk = 0; kk < 15; kk++) {
                const float4 v4 = *(const float4*)(&sU[(g * 15 + kk) * EDIM + c]);
                acc[kk] += w4.x * v4.x + w4.y * v4.y + w4.z * v4.z + w4.w * v4.w;
            }
        }
        const float bo = head_b[o];
        #pragma unroll
        for (int kk = 0; kk < 15; kk++) {
            int k = g * 15 + kk;
            sX[k * HIDC + o] = (sSel[k] >= 0) ? (acc[kk] + bo) : 0.0f;
        }
    }
    __syncthreads();

    // ---- Phase B: token mixer
    ln_rows30(sX, sT, ln_t_g, ln_t_b, wave, lane);   // sT = LN_t(x)
    __syncthreads();
    for (int idx = t; idx < 1500; idx += BLK) {      // y15[j][i]
        int i = idx / 100, j = idx - i * 100;
        float a = tok1_b[i];
        #pragma unroll
        for (int k = 0; k < KTOK; k++) a += tok1_w[i * KTOK + k] * sT[k * HIDC + j];
        sU[j * 15 + i] = gelu_exact(a);
    }
    __syncthreads();
    for (int idx = t; idx < 3000; idx += BLK) {      // h_token = tok2(y15) + x
        int k2 = idx / 100, j = idx - k2 * 100;
        float a = tok2_b[k2];
        #pragma unroll
        for (int i = 0; i < 15; i++) a += tok2_w[k2 * 15 + i] * sU[j * 15 + i];
        sT[k2 * HIDC + j] = a + sX[k2 * HIDC + j];
    }
    __syncthreads();

    // ---- Phase C: channel mixer (two halves of 15 tokens; H4 half fits sU)
    ln_rows30(sT, sX, ln_c_g, ln_c_b, wave, lane);   // sX = LN_c(h_token); x is dead
    __syncthreads();
    for (int half = 0; half < 2; half++) {
        {   // ch1: [15,100] @ [100,400] -> GELU -> sU[15][400]
            const bool two = (t < 144);
            float acc0[15], acc1[15];
            #pragma unroll
            for (int kk = 0; kk < 15; kk++) { acc0[kk] = 0.0f; acc1[kk] = 0.0f; }
            const float* w0 = ch1_w + t * HIDC;
            const float* w1 = ch1_w + (t + 256) * HIDC;
            for (int c = 0; c < HIDC; c += 4) {
                const float4 wa = *(const float4*)(w0 + c);
                float4 wb = make_float4(0.f, 0.f, 0.f, 0.f);
                if (two) wb = *(const float4*)(w1 + c);
                #pragma unroll
                for (int kk = 0; kk < 15; kk++) {
                    const float4 v = *(const float4*)(&sX[(half * 15 + kk) * HIDC + c]);
                    acc0[kk] += wa.x * v.x + wa.y * v.y + wa.z * v.z + wa.w * v.w;
                    acc1[kk] += wb.x * v.x + wb.y * v.y + wb.z * v.z + wb.w * v.w;
                }
            }
            const float b0 = ch1_b[t];
            const float b1 = two ? ch1_b[t + 256] : 0.0f;
            #pragma unroll
            for (int kk = 0; kk < 15; kk++) {
                sU[kk * 400 + t] = gelu_exact(acc0[kk] + b0);
                if (two) sU[kk * 400 + t + 256] = gelu_exact(acc1[kk] + b1);
            }
        }
        __syncthreads();
        if (t < 200) {  // ch2: [15,400] @ [400,100] + residual into sT
            const int gg = t / 100, j = t - gg * 100;
            const int k0 = gg * 8;
            float acc[8];
            #pragma unroll
            for (int kk = 0; kk < 8; kk++) acc[kk] = 0.0f;
            const float* wrow = ch2_w + j * 400;
            for (int c = 0; c < 400; c += 4) {
                const float4 w4 = *(const float4*)(wrow + c);
                #pragma unroll
                for (int kk = 0; kk < 8; kk++) {
                    if (k0 + kk < 15) {
                        const float4 v = *(const float4*)(&sU[(k0 + kk) * 400 + c]);
                        acc[kk] += w4.x * v.x + w4.y * v.y + w4.z * v.z + w4.w * v.w;
                    }
                }
            }
            const float bj = ch2_b[j];
            #pragma unroll
            for (int kk = 0; kk < 8; kk++) {
                if (k0 + kk < 15) {
                    int k = half * 15 + k0 + kk;
                    sT[k * HIDC + j] += acc[kk] + bj;
                }
            }
        }
        __syncthreads();
    }

    // ---- Phase D: LN_h + mean over K + output matmul
    {
        float a0 = 0.0f, a1 = 0.0f;
        for (int k = wave; k < KTOK; k += 4) {
            const float* row = sT + k * HIDC;
            float x0 = row[lane];
            float x1 = (lane < 36) ? row[64 + lane] : 0.0f;
            float s = x0 + x1;
            #pragma unroll
            for (int off = 32; off > 0; off >>= 1) s += __shfl_xor(s, off);
            float m = s * 0.01f;
            float d0 = x0 - m, d1 = x1 - m;
            float sq = d0 * d0 + ((lane < 36) ? d1 * d1 : 0.0f);
            #pragma unroll
            for (int off = 32; off > 0; off >>= 1) sq += __shfl_xor(sq, off);
            float rs = rsqrtf(sq * 0.01f + 1e-5f);
            a0 += d0 * rs * ln_h_g[lane] + ln_h_b[lane];
            if (lane < 36) a1 += d1 * rs * ln_h_g[64 + lane] + ln_h_b[64 + lane];
        }
        sAcc[wave * 100 + lane] = a0;
        if (lane < 36) sAcc[wave * 100 + 64 + lane] = a1;
    }
    __syncthreads();
    if (t < 100) sTsum[t] = (sAcc[t] + sAcc[100 + t] + sAcc[200 + t] + sAcc[300 + t]) * (1.0f / 30.0f);
    __syncthreads();
    if (t < 100) {
        float a = out_b[t];
        const float* wrow = out_w + t * HIDC;
        for (int c = 0; c < HIDC; c += 4) {
            const float4 w4 = *(const float4*)(wrow + c);
            const float4 v4 = *(const float4*)(&sTsum[c]);
            a += w4.x * v4.x + w4.y * v4.y + w4.z * v4.z + w4.w * v4.w;
        }
        out[(long long)node * HIDC + t] = a;
    }
}

// ---------------------------------------------------------------- launch

extern "C" void kernel_launch(void* const* d_in, const int* in_sizes, int n_in,
                              void* d_out, int out_size, void* d_ws, size_t ws_size,
                              hipStream_t stream) {
    const float* edge_attr  = (const float*)d_in[0];
    const float* edge_time  = (const float*)d_in[1];
    const int*   node_batch = (const int*)d_in[2];
    // d_in[3] = num_nodes scalar (value known from out_size)
    const float* head_w = (const float*)d_in[4];
    const float* head_b = (const float*)d_in[5];
    const float* ln_t_g = (const float*)d_in[6];
    const float* ln_t_b = (const float*)d_in[7];
    const float* tok1_w = (const float*)d_in[8];
    const float* tok1_b = (const float*)d_in[9];
    const float* tok2_w = (const float*)d_in[10];
    const float* tok2_b = (const float*)d_in[11];
    const float* ln_c_g = (const float*)d_in[12];
    const float* ln_c_b = (const float*)d_in[13];
    const float* ch1_w  = (const float*)d_in[14];
    const float* ch1_b  = (const float*)d_in[15];
    const float* ch2_w  = (const float*)d_in[16];
    const float* ch2_b  = (const float*)d_in[17];
    const float* ln_h_g = (const float*)d_in[18];
    const float* ln_h_b = (const float*)d_in[19];
    const float* out_w  = (const float*)d_in[20];
    const float* out_b  = (const float*)d_in[21];
    float* out = (float*)d_out;

    const int E = in_sizes[2];
    const int N = out_size / HIDC;

    int* cnt     = (int*)d_ws;          // N
    int* cursor  = cnt + N;             // N
    int* offsets = cursor + N;          // N
    int* order   = offsets + N;         // E
    int* sel     = order + E;           // N*K

    hipMemsetAsync(cnt, 0, (size_t)2 * N * sizeof(int), stream);
    count_kernel<<<(E + 255) / 256, 256, 0, stream>>>(node_batch, cnt, E);
    scan_kernel<<<1, SCAN_T, 0, stream>>>(cnt, offsets, N);
    fill_kernel<<<(E + 255) / 256, 256, 0, stream>>>(node_batch, cursor, offsets, order, E);
    select_kernel<<<(N + 255) / 256, 256, 0, stream>>>(cnt, offsets, order, sel, N);
    fused_node_kernel<<<N, BLK, 0, stream>>>(
        edge_attr, edge_time, sel, head_w, head_b,
        ln_t_g, ln_t_b, tok1_w, tok1_b, tok2_w, tok2_b,
        ln_c_g, ln_c_b, ch1_w, ch1_b, ch2_w, ch2_b,
        ln_h_g, ln_h_b, out_w, out_b, out);
}